// Round 1
// baseline (355.561 us; speedup 1.0000x reference)
//
#include <hip/hip_runtime.h>
#include <cstdint>
#include <cstddef>

// CoaT factorized attention block, MI355X/gfx950.
// R6: GEMM K-loop converted from single-buffered 2-barrier structure to
// double-buffered 2-phase pipeline (T3 minimum recipe): issue next K-tile's
// global_load_lds BEFORE computing current tile, ONE __syncthreads per
// K-step (drains vmcnt after the MFMA window instead of before it).
// LDS 48->96 KB (1 blk/CU; in-block pipeline does the hiding, HK precedent).
// setprio(1) around MFMA cluster (T5; stage/compute role split now exists).
// Staging indices, XOR-8 swizzle, XCD banding unchanged from R5.

typedef unsigned short u16;

#define HEADS 8
#define CHD   64
#define CDIM  512
#define NTOK  785
#define BATCH 32
#define MROWS (BATCH * NTOK)   // 25120
#define MPAD  25344            // 99 * 256
#define QKVN  1536
#define IMGHW 784
#define KVSPLIT 7

typedef float  f32x4  __attribute__((ext_vector_type(4)));
typedef __bf16 bf16x8 __attribute__((ext_vector_type(8)));

__device__ __forceinline__ u16 f2bf(float f) {
  union { float f; uint32_t u; } x; x.f = f;
  uint32_t r = x.u + 0x7fffu + ((x.u >> 16) & 1u);  // RNE
  return (u16)(r >> 16);
}
__device__ __forceinline__ float bf2f(u16 u) {
  union { uint32_t u; float f; } x; x.u = ((uint32_t)u) << 16;
  return x.f;
}
// packed f32x2 -> bf16x2 (low = a, high = b)
__device__ __forceinline__ uint32_t pk2(float a, float b) {
#if __has_builtin(__builtin_amdgcn_cvt_pk_bf16_f32)
  auto v = __builtin_amdgcn_cvt_pk_bf16_f32(a, b);
  union { decltype(v) v2; uint32_t u; } cv; cv.v2 = v; return cv.u;
#else
  return (uint32_t)f2bf(a) | ((uint32_t)f2bf(b) << 16);
#endif
}

// ---------------- merged f32 -> bf16 casts (x, qkv_w, proj_w) --------------
__global__ __launch_bounds__(256)
void casts_kernel(const float* __restrict__ x, u16* __restrict__ xb,
                  const float* __restrict__ w1, u16* __restrict__ w1b,
                  const float* __restrict__ w2, u16* __restrict__ w2b) {
  const int N1 = MROWS * CDIM / 4, N2 = QKVN * CDIM / 4, N3 = CDIM * CDIM / 4;
  int i = blockIdx.x * 256 + threadIdx.x;
  const float* src; u16* dst;
  if (i < N1)           { src = x;  dst = xb;  }
  else if (i < N1 + N2) { i -= N1;  src = w1; dst = w1b; }
  else if (i < N1 + N2 + N3) { i -= N1 + N2; src = w2; dst = w2b; }
  else return;
  float4 v = reinterpret_cast<const float4*>(src)[i];
  uint2 o; o.x = pk2(v.x, v.y); o.y = pk2(v.z, v.w);
  reinterpret_cast<uint2*>(dst)[i] = o;
}

// ---------------- async global->LDS, 16B per lane --------------------------
__device__ __forceinline__ void gld_lds16(const u16* g, u16* l) {
  __builtin_amdgcn_global_load_lds((__attribute__((address_space(1))) void*)g,
                                   (__attribute__((address_space(3))) void*)l,
                                   16, 0, 0);
}

// ---------------- bf16 MFMA GEMM, C = A @ W^T + bias -----------------------
// 256x128 tile, 512 threads = 8 waves in 4(row)x2(col); per wave 4x4 of
// 16x16x32 MFMA. BK=64 with XOR-8 chunk swizzle (global-side permutation:
// logical chunk c of row r lands at physical chunk c^(r&7); fragment reads
// hit 8 distinct bank-groups -> free 2-way only).
// Double-buffered LDS, 2-phase pipeline:
//   prologue: STAGE(buf0, k0=0); barrier
//   loop:     STAGE(buf[cur^1], k0+64); ds_read+MFMA from buf[cur];
//             barrier (drains vmcnt AFTER the MFMA window); cur^=1
// Grid: flat 1D, XCD-banded, N-fastest (xcd = flat&7) -> A-tile read ~once
// per XCD L2.
template <int OUTBF16>
__global__ __launch_bounds__(512)
void gemm_bt(const u16* __restrict__ A, const u16* __restrict__ W,
             const float* __restrict__ bias, void* __restrict__ Cout,
             int Mstore, int N, int K, int nMt, int nNt) {
  __shared__ __align__(16) u16 lsA[2][256 * 64];   // 64 KB
  __shared__ __align__(16) u16 lsB[2][128 * 64];   // 32 KB
  const int flat = blockIdx.x;
  const int xcd = flat & 7, idx = flat >> 3;
  const int nt = idx % nNt;
  const int mt = (idx / nNt) * 8 + xcd;
  if (mt >= nMt) return;
  const int tile_m = mt * 256, tile_n = nt * 128;

  const int tid  = threadIdx.x;
  const int wave = tid >> 6, lane = tid & 63;
  const int quad = lane >> 4, l16 = lane & 15;
  const int wm = (wave & 3) * 64, wn = (wave >> 2) * 64;

  // staging: thread covers row s*64 + (tid>>3); loads global chunk
  // ((tid&7) ^ (row&7)) -> lands at physical chunk (tid&7).
  const int srow0 = tid >> 3;                        // 0..63
  const int scol  = ((tid & 7) ^ (srow0 & 7)) * 8;
  const int ldst  = srow0 * 64 + (tid & 7) * 8;      // + s*4096 (elems)

  f32x4 acc[4][4] = {};

  // prologue: stage K-tile 0 into buffer 0
#pragma unroll
  for (int s = 0; s < 4; ++s)
    gld_lds16(A + (size_t)(tile_m + s * 64 + srow0) * K + scol,
              &lsA[0][s * 4096 + ldst]);
#pragma unroll
  for (int s = 0; s < 2; ++s)
    gld_lds16(W + (size_t)(tile_n + s * 64 + srow0) * K + scol,
              &lsB[0][s * 4096 + ldst]);
  __syncthreads();

  int cur = 0;
  for (int k0 = 0; k0 < K; k0 += 64) {
    // issue next K-tile's loads into the other buffer (overlaps with MFMA)
    if (k0 + 64 < K) {
      const int kn = k0 + 64;
#pragma unroll
      for (int s = 0; s < 4; ++s)
        gld_lds16(A + (size_t)(tile_m + s * 64 + srow0) * K + kn + scol,
                  &lsA[cur ^ 1][s * 4096 + ldst]);
#pragma unroll
      for (int s = 0; s < 2; ++s)
        gld_lds16(W + (size_t)(tile_n + s * 64 + srow0) * K + kn + scol,
                  &lsB[cur ^ 1][s * 4096 + ldst]);
    }
    // compute current buffer
#pragma unroll
    for (int kk = 0; kk < 2; ++kk) {
      const int pch = ((kk * 4 + quad) ^ (l16 & 7)) * 8;  // physical chunk
      bf16x8 af[4], bfr[4];
#pragma unroll
      for (int i = 0; i < 4; ++i) {
        af[i]  = *reinterpret_cast<const bf16x8*>(&lsA[cur][(wm + i * 16 + l16) * 64 + pch]);
        bfr[i] = *reinterpret_cast<const bf16x8*>(&lsB[cur][(wn + i * 16 + l16) * 64 + pch]);
      }
      __builtin_amdgcn_s_setprio(1);
#pragma unroll
      for (int i = 0; i < 4; ++i)
#pragma unroll
        for (int j = 0; j < 4; ++j)
          acc[i][j] = __builtin_amdgcn_mfma_f32_16x16x32_bf16(af[i], bfr[j], acc[i][j], 0, 0, 0);
      __builtin_amdgcn_s_setprio(0);
    }
    // one barrier per K-step; __syncthreads drains vmcnt (next tile staged)
    // and lgkmcnt, and syncs waves so nobody overwrites a buffer in use.
    __syncthreads();
    cur ^= 1;
  }

  // C/D layout: col = lane&15, row = quad*4 + reg
#pragma unroll
  for (int i = 0; i < 4; ++i) {
    const int mbase = tile_m + wm + i * 16 + quad * 4;
#pragma unroll
    for (int j = 0; j < 4; ++j) {
      const int n  = tile_n + wn + j * 16 + l16;
      const float bv = bias[n];
      const float v0 = acc[i][j][0] + bv, v1 = acc[i][j][1] + bv;
      const float v2 = acc[i][j][2] + bv, v3 = acc[i][j][3] + bv;
      if (OUTBF16) {
        u16* cp = reinterpret_cast<u16*>(Cout) + (size_t)mbase * N + n;
        const uint32_t p01 = pk2(v0, v1), p23 = pk2(v2, v3);
        if (mbase + 0 < Mstore) cp[0]            = (u16)p01;
        if (mbase + 1 < Mstore) cp[(size_t)N]    = (u16)(p01 >> 16);
        if (mbase + 2 < Mstore) cp[(size_t)N*2]  = (u16)p23;
        if (mbase + 3 < Mstore) cp[(size_t)N*3]  = (u16)(p23 >> 16);
      } else {
        float* cp = reinterpret_cast<float*>(Cout) + (size_t)mbase * N + n;
        if (mbase + 0 < Mstore) cp[0]           = v0;
        if (mbase + 1 < Mstore) cp[(size_t)N]   = v1;
        if (mbase + 2 < Mstore) cp[(size_t)N*2] = v2;
        if (mbase + 3 < Mstore) cp[(size_t)N*3] = v3;
      }
    }
  }
}

// ---------------- kv partials + exp-sum partials ---------------------------
// kvpart[bh][split][c][d] = sum_{n in split} exp(k[n,c]) * v[n,d]
// kvsum [bh][split][c]    = sum_{n in split} exp(k[n,c])
// No max subtraction: k ~ N(0,1), |k| small -> exp safe in f32.
__global__ __launch_bounds__(256)
void kv_kernel(const u16* __restrict__ qkv, float* __restrict__ kvpart,
               float* __restrict__ kvsum) {
  const int bh = blockIdx.x, split = blockIdx.y;
  const int b = bh >> 3, h = bh & 7;
  const int n_start = split * 113;
  const int n_end = min(NTOK, n_start + 113);
  const int t = threadIdx.x;
  const int d = t & 63, cq = t >> 6;
  __shared__ float e_s[32 * 64];
  __shared__ float v_s[32 * 64];
  const u16* kbase = qkv + (size_t)(b * NTOK) * QKVN + CDIM + h * CHD;
  const u16* vbase = kbase + CDIM;
  float acc[16];
#pragma unroll
  for (int i = 0; i < 16; ++i) acc[i] = 0.f;
  float s_part = 0.f;   // sum of exp over this thread's staged elems (c = t&63)

  for (int n0 = n_start; n0 < n_end; n0 += 32) {
    const int nc = min(32, n_end - n0);
    __syncthreads();
    for (int i = t; i < nc * 64; i += 256) {
      const int nl = i >> 6, c = i & 63;
      const float e = __expf(bf2f(kbase[(size_t)(n0 + nl) * QKVN + c]));
      e_s[i] = e; s_part += e;
      v_s[i] = bf2f(vbase[(size_t)(n0 + nl) * QKVN + c]);
    }
    __syncthreads();
    for (int nl = 0; nl < nc; ++nl) {
      const float vv = v_s[nl * 64 + d];
#pragma unroll
      for (int i = 0; i < 16; ++i)
        acc[i] += e_s[nl * 64 + cq * 16 + i] * vv;
    }
  }
#pragma unroll
  for (int i = 0; i < 16; ++i) {
    const int c = cq * 16 + i;
    kvpart[(((size_t)bh * KVSPLIT + split) * 64 + c) * 64 + d] = acc[i];
  }
  __syncthreads();
  e_s[t] = s_part;
  __syncthreads();
  if (t < 64)
    kvsum[((size_t)bh * KVSPLIT + split) * 64 + t] =
        e_s[t] + e_s[64 + t] + e_s[128 + t] + e_s[192 + t];
}

// ---------------- reduce partials -> kvT[bh][d][c] bf16 (B-operand layout) -
__global__ __launch_bounds__(256)
void kv_reduce_kernel(const float* __restrict__ kvpart, const float* __restrict__ kvsum,
                      u16* __restrict__ kvT) {
  const int bh = blockIdx.x;
  const int t = threadIdx.x;
  const int d = t & 63, cq = t >> 6;
#pragma unroll
  for (int cc = 0; cc < 16; ++cc) {
    const int c = cq * 16 + cc;
    float s = 0.f, S = 0.f;
#pragma unroll
    for (int sp = 0; sp < KVSPLIT; ++sp) {
      s += kvpart[(((size_t)bh * KVSPLIT + sp) * 64 + c) * 64 + d];
      S += kvsum[((size_t)bh * KVSPLIT + sp) * 64 + c];
    }
    kvT[(size_t)bh * 4096 + d * 64 + c] = f2bf(s / S);
  }
}

// ---------------- depthwise conv + EV fuse ---------------------------------
template <int KS>
__device__ __forceinline__ void conv_head(
    const u16* __restrict__ qkv, const float* __restrict__ wgt,
    const float* __restrict__ bias, int b, int head, int hh, int yt,
    u16* __restrict__ evbuf, u16* __restrict__ ls) {
  constexpr int PAD = KS / 2;
  constexpr int RIN = 4 + 2 * PAD;
  const int t = threadIdx.x;
  const int y0 = yt * 4;
  const u16* vimg = qkv + (size_t)(b * NTOK + 1) * QKVN + 2 * CDIM + head * 64;
  const int c8 = (t & 7) * 8;
  for (int pi = t >> 3; pi < RIN * 28; pi += 32) {
    const int ry = pi / 28, rx = pi - ry * 28;
    const int yy = y0 - PAD + ry;
    uint4 val = {0, 0, 0, 0};
    if (yy >= 0 && yy < 28)
      val = *reinterpret_cast<const uint4*>(vimg + (size_t)(yy * 28 + rx) * QKVN + c8);
    *reinterpret_cast<uint4*>(ls + pi * 64 + c8) = val;
  }
  __syncthreads();
  const int d = t & 63, yl = t >> 6;
  float wr[KS * KS];
  const float* wp = wgt + (hh * 64 + d) * KS * KS;
#pragma unroll
  for (int i = 0; i < KS * KS; ++i) wr[i] = wp[i];
  const float bv = bias[hh * 64 + d];
  float acc[28];
#pragma unroll
  for (int x = 0; x < 28; ++x) acc[x] = bv;
#pragma unroll
  for (int xx = 0; xx < 28; ++xx) {
    float col[KS];
#pragma unroll
    for (int r = 0; r < KS; ++r)
      col[r] = bf2f(ls[((yl + r) * 28 + xx) * 64 + d]);
#pragma unroll
    for (int j = 0; j < KS; ++j) {
      const int x = xx + PAD - j;
      if (x >= 0 && x < 28) {
#pragma unroll
        for (int r = 0; r < KS; ++r)
          acc[x] += col[r] * wr[r * KS + j];
      }
    }
  }
  const int p0 = (y0 + yl) * 28;
  const u16* qrow = qkv + (size_t)(b * NTOK + 1 + p0) * QKVN + head * 64 + d;
  u16* obase = evbuf + (((size_t)(b * 8 + head)) * IMGHW + p0) * 64 + d;
#pragma unroll
  for (int x = 0; x < 28; ++x) {
    const float ev = acc[x] * bf2f(qrow[(size_t)x * QKVN]);
    obase[(size_t)x * 64] = f2bf(ev);
  }
}

__global__ __launch_bounds__(256)
void conv_all_kernel(const u16* __restrict__ qkv,
                     const float* __restrict__ w3, const float* __restrict__ b3,
                     const float* __restrict__ w5, const float* __restrict__ b5,
                     const float* __restrict__ w7, const float* __restrict__ b7,
                     u16* __restrict__ evbuf) {
  __shared__ __align__(16) u16 ls[10 * 28 * 64];
  const int b = blockIdx.x, h = blockIdx.y, yt = blockIdx.z;
  if (h < 2)      conv_head<3>(qkv, w3, b3, b, h, h,     yt, evbuf, ls);
  else if (h < 5) conv_head<5>(qkv, w5, b5, b, h, h - 2, yt, evbuf, ls);
  else            conv_head<7>(qkv, w7, b7, b, h, h - 5, yt, evbuf, ls);
}

// ---------------- combine: factor_att via MFMA + CRPE ----------------------
__global__ __launch_bounds__(256)
void combine_kernel(const u16* __restrict__ qkv, const u16* __restrict__ kvT,
                    const u16* __restrict__ evbuf, u16* __restrict__ attn) {
  const int bh = blockIdx.x;
  const int b = bh >> 3, h = bh & 7;
  const int wave = threadIdx.x >> 6, lane = threadIdx.x & 63;
  const int quad = lane >> 4, l16 = lane & 15;
  const int tokbase = blockIdx.y * 256 + wave * 64;

  const u16* kvb = kvT + (size_t)bh * 4096;
  bf16x8 bfr[4][2];
#pragma unroll
  for (int j = 0; j < 4; ++j)
#pragma unroll
    for (int kk = 0; kk < 2; ++kk)
      bfr[j][kk] = *reinterpret_cast<const bf16x8*>(
          &kvb[(j * 16 + l16) * 64 + kk * 32 + quad * 8]);

  bf16x8 af[4][2];
#pragma unroll
  for (int i = 0; i < 4; ++i) {
    const int tok = min(tokbase + i * 16 + l16, NTOK - 1);
    const u16* qrow = qkv + (size_t)(b * NTOK + tok) * QKVN + h * CHD;
    af[i][0] = *reinterpret_cast<const bf16x8*>(&qrow[quad * 8]);
    af[i][1] = *reinterpret_cast<const bf16x8*>(&qrow[32 + quad * 8]);
  }

  f32x4 acc[4][4] = {};
#pragma unroll
  for (int kk = 0; kk < 2; ++kk)
#pragma unroll
    for (int i = 0; i < 4; ++i)
#pragma unroll
      for (int j = 0; j < 4; ++j)
        acc[i][j] = __builtin_amdgcn_mfma_f32_16x16x32_bf16(af[i][kk], bfr[j][kk], acc[i][j], 0, 0, 0);

  const float scale = 0.125f;
  const u16* evb = evbuf + (size_t)bh * IMGHW * 64;
#pragma unroll
  for (int i = 0; i < 4; ++i) {
#pragma unroll
    for (int r = 0; r < 4; ++r) {
      const int tok = tokbase + i * 16 + quad * 4 + r;
      if (tok < NTOK) {
#pragma unroll
        for (int j = 0; j < 4; ++j) {
          const int d = j * 16 + l16;
          float out = scale * acc[i][j][r];
          if (tok > 0) out += bf2f(evb[(size_t)(tok - 1) * 64 + d]);
          attn[(size_t)(b * NTOK + tok) * CDIM + h * CHD + d] = f2bf(out);
        }
      }
    }
  }
}

// ---------------- launch ---------------------------------------------------
extern "C" void kernel_launch(void* const* d_in, const int* in_sizes, int n_in,
                              void* d_out, int out_size, void* d_ws, size_t ws_size,
                              hipStream_t stream) {
  const float* x      = (const float*)d_in[0];
  const float* qkv_w  = (const float*)d_in[1];
  const float* qkv_b  = (const float*)d_in[2];
  const float* proj_w = (const float*)d_in[3];
  const float* proj_b = (const float*)d_in[4];
  const float* w3 = (const float*)d_in[5];
  const float* b3 = (const float*)d_in[6];
  const float* w5 = (const float*)d_in[7];
  const float* b5 = (const float*)d_in[8];
  const float* w7 = (const float*)d_in[9];
  const float* b7 = (const float*)d_in[10];
  float* out = (float*)d_out;

  char* p = (char*)d_ws;
  u16* xb    = (u16*)p;   p += (size_t)MPAD * CDIM * 2;
  u16* wqb   = (u16*)p;   p += (size_t)QKVN * CDIM * 2;
  u16* wpb   = (u16*)p;   p += (size_t)CDIM * CDIM * 2;
  u16* qkvb  = (u16*)p;   p += (size_t)MPAD * QKVN * 2;
  float* kvsum = (float*)p; p += (size_t)256 * KVSPLIT * 64 * 4;
  u16* kvT   = (u16*)p;   p += (size_t)256 * 64 * 64 * 2;
  // kvpart (f32, 29.4 MB) and evbuf (bf16, 25.7 MB) share one region:
  // kvpart dead after kv_reduce; conv writes evbuf afterwards.
  char* shared_region = p;
  float* kvpart = (float*)shared_region;
  u16*   evbuf  = (u16*)shared_region;
  p += (size_t)256 * KVSPLIT * 64 * 64 * 4;
  u16* attn  = (u16*)p;   p += (size_t)MPAD * CDIM * 2;

  // 1. casts (single launch)
  {
    const int total = MROWS * CDIM / 4 + QKVN * CDIM / 4 + CDIM * CDIM / 4;
    casts_kernel<<<(total + 255) / 256, 256, 0, stream>>>(x, xb, qkv_w, wqb, proj_w, wpb);
  }
  // 2. qkv = x @ qkv_w^T + qkv_b  (bf16 out). nMt=99, nNt=12, XCD-banded grid.
  gemm_bt<1><<<13 * 8 * 12, 512, 0, stream>>>(xb, wqb, qkv_b, qkvb,
                                              MPAD, QKVN, CDIM, 99, 12);
  // 3. kv partials + exp-sums
  kv_kernel<<<dim3(256, KVSPLIT), 256, 0, stream>>>(qkvb, kvpart, kvsum);
  kv_reduce_kernel<<<256, 256, 0, stream>>>(kvpart, kvsum, kvT);
  // 4. depthwise convs + EV fuse
  conv_all_kernel<<<dim3(BATCH, HEADS, 7), 256, 0, stream>>>(
      qkvb, w3, b3, w5, b5, w7, b7, evbuf);
  // 5. factor_att + CRPE -> attn (bf16)
  combine_kernel<<<dim3(256, 4), 256, 0, stream>>>(qkvb, kvT, evbuf, attn);
  // 6. out = attn @ proj_w^T + proj_b  (f32 out). nMt=99, nNt=4.
  gemm_bt<0><<<13 * 8 * 4, 512, 0, stream>>>(attn, wpb, proj_b, out,
                                             MROWS, CDIM, CDIM, 99, 4);
}

// Round 2
// 344.064 us; speedup vs baseline: 1.0334x; 1.0334x over previous
//
#include <hip/hip_runtime.h>
#include <cstdint>
#include <cstddef>

// CoaT factorized attention block, MI355X/gfx950.
// R7: GEMM pipeline rebuilt per T3+T4 (counted vmcnt, raw s_barrier) after R6
// post-mortem showed __syncthreads() drains the prefetch at every K-step.
// Per K-tile: {ds_read 16 frags; MFMA kk0; lgkmcnt(0); s_barrier;
// STAGE(t+2) into just-freed buffer; MFMA kk1; vmcnt(6); s_barrier}.
// vmcnt never drains to 0 in the main loop (6 newest loads = tile t+2 stay
// in flight across the barrier). K=512 hardcoded as KT=8 tiles of 64.
// Tile geometry / XOR-8 swizzle / XCD banding unchanged from R5.

typedef unsigned short u16;

#define HEADS 8
#define CHD   64
#define CDIM  512
#define NTOK  785
#define BATCH 32
#define MROWS (BATCH * NTOK)   // 25120
#define MPAD  25344            // 99 * 256
#define QKVN  1536
#define IMGHW 784
#define KVSPLIT 7

typedef float  f32x4  __attribute__((ext_vector_type(4)));
typedef __bf16 bf16x8 __attribute__((ext_vector_type(8)));

__device__ __forceinline__ u16 f2bf(float f) {
  union { float f; uint32_t u; } x; x.f = f;
  uint32_t r = x.u + 0x7fffu + ((x.u >> 16) & 1u);  // RNE
  return (u16)(r >> 16);
}
__device__ __forceinline__ float bf2f(u16 u) {
  union { uint32_t u; float f; } x; x.u = ((uint32_t)u) << 16;
  return x.f;
}
// packed f32x2 -> bf16x2 (low = a, high = b)
__device__ __forceinline__ uint32_t pk2(float a, float b) {
#if __has_builtin(__builtin_amdgcn_cvt_pk_bf16_f32)
  auto v = __builtin_amdgcn_cvt_pk_bf16_f32(a, b);
  union { decltype(v) v2; uint32_t u; } cv; cv.v2 = v; return cv.u;
#else
  return (uint32_t)f2bf(a) | ((uint32_t)f2bf(b) << 16);
#endif
}

// ---------------- merged f32 -> bf16 casts (x, qkv_w, proj_w) --------------
__global__ __launch_bounds__(256)
void casts_kernel(const float* __restrict__ x, u16* __restrict__ xb,
                  const float* __restrict__ w1, u16* __restrict__ w1b,
                  const float* __restrict__ w2, u16* __restrict__ w2b) {
  const int N1 = MROWS * CDIM / 4, N2 = QKVN * CDIM / 4, N3 = CDIM * CDIM / 4;
  int i = blockIdx.x * 256 + threadIdx.x;
  const float* src; u16* dst;
  if (i < N1)           { src = x;  dst = xb;  }
  else if (i < N1 + N2) { i -= N1;  src = w1; dst = w1b; }
  else if (i < N1 + N2 + N3) { i -= N1 + N2; src = w2; dst = w2b; }
  else return;
  float4 v = reinterpret_cast<const float4*>(src)[i];
  uint2 o; o.x = pk2(v.x, v.y); o.y = pk2(v.z, v.w);
  reinterpret_cast<uint2*>(dst)[i] = o;
}

// ---------------- async global->LDS, 16B per lane --------------------------
__device__ __forceinline__ void gld_lds16(const u16* g, u16* l) {
  __builtin_amdgcn_global_load_lds((__attribute__((address_space(1))) void*)g,
                                   (__attribute__((address_space(3))) void*)l,
                                   16, 0, 0);
}

// ---------------- bf16 MFMA GEMM, C = A @ W^T + bias -----------------------
// 256x128 tile, 512 threads = 8 waves in 4(row)x2(col); per wave 4x4 of
// 16x16x32 MFMA. BK=64 with XOR-8 chunk swizzle (global-side permutation:
// logical chunk c of row r lands at physical chunk c^(r&7); fragment reads
// hit 8 distinct bank-groups -> free 2-way only).
// Double-buffered LDS (96 KB, 1 blk/CU), 2-deep pipeline with counted vmcnt:
// the 6 loads of tile t+2 stay in flight across the end-of-step barrier.
// K MUST be 512 (KT=8) — both call sites satisfy this.
// Grid: flat 1D, XCD-banded, N-fastest (xcd = flat&7).
template <int OUTBF16>
__global__ __launch_bounds__(512)
void gemm_bt(const u16* __restrict__ A, const u16* __restrict__ W,
             const float* __restrict__ bias, void* __restrict__ Cout,
             int Mstore, int N, int K, int nMt, int nNt) {
  constexpr int KT = 8;                           // K/64; K==512 at call sites
  __shared__ __align__(16) u16 lsA[2][256 * 64];  // 64 KB
  __shared__ __align__(16) u16 lsB[2][128 * 64];  // 32 KB
  const int flat = blockIdx.x;
  const int xcd = flat & 7, idx = flat >> 3;
  const int nt = idx % nNt;
  const int mt = (idx / nNt) * 8 + xcd;
  if (mt >= nMt) return;
  const int tile_m = mt * 256, tile_n = nt * 128;

  const int tid  = threadIdx.x;
  const int wave = tid >> 6, lane = tid & 63;
  const int quad = lane >> 4, l16 = lane & 15;
  const int wm = (wave & 3) * 64, wn = (wave >> 2) * 64;

  // staging: thread covers row s*64 + (tid>>3); loads global chunk
  // ((tid&7) ^ (row&7)) -> lands at physical chunk (tid&7).
  const int srow0 = tid >> 3;                        // 0..63
  const int scol  = ((tid & 7) ^ (srow0 & 7)) * 8;
  const int ldst  = srow0 * 64 + (tid & 7) * 8;      // + s*4096 (elems)

  auto stage = [&](int kt, int buf) {
    const int kc = kt * 64 + scol;
#pragma unroll
    for (int s = 0; s < 4; ++s)
      gld_lds16(A + (size_t)(tile_m + s * 64 + srow0) * K + kc,
                &lsA[buf][s * 4096 + ldst]);
#pragma unroll
    for (int s = 0; s < 2; ++s)
      gld_lds16(W + (size_t)(tile_n + s * 64 + srow0) * K + kc,
                &lsB[buf][s * 4096 + ldst]);
  };

  f32x4 acc[4][4] = {};

  // prologue: stage tiles 0 and 1 (12 loads in flight)
  stage(0, 0);
  stage(1, 1);
  asm volatile("s_waitcnt vmcnt(6)" ::: "memory");   // tile0 landed
  __builtin_amdgcn_sched_barrier(0);
  __builtin_amdgcn_s_barrier();
  __builtin_amdgcn_sched_barrier(0);

#pragma unroll
  for (int t = 0; t < KT; ++t) {
    const int cur = t & 1;
    // ds_read ALL fragments of this K-tile (kk0 first so its MFMAs start asap)
    bf16x8 af[2][4], bfr[2][4];
#pragma unroll
    for (int kk = 0; kk < 2; ++kk) {
      const int pch = ((kk * 4 + quad) ^ (l16 & 7)) * 8;  // physical chunk
#pragma unroll
      for (int i = 0; i < 4; ++i) {
        af[kk][i]  = *reinterpret_cast<const bf16x8*>(
            &lsA[cur][(wm + i * 16 + l16) * 64 + pch]);
        bfr[kk][i] = *reinterpret_cast<const bf16x8*>(
            &lsB[cur][(wn + i * 16 + l16) * 64 + pch]);
      }
    }
    // kk0 MFMAs (compiler inserts precise lgkmcnt for operand readiness;
    // kk1 ds_reads complete underneath)
    __builtin_amdgcn_s_setprio(1);
#pragma unroll
    for (int i = 0; i < 4; ++i)
#pragma unroll
      for (int j = 0; j < 4; ++j)
        acc[i][j] = __builtin_amdgcn_mfma_f32_16x16x32_bf16(
            af[0][i], bfr[0][j], acc[i][j], 0, 0, 0);
    __builtin_amdgcn_s_setprio(0);
    // all 16 frags now needed in regs -> buffer is free after the barrier
    asm volatile("s_waitcnt lgkmcnt(0)" ::: "memory");
    __builtin_amdgcn_sched_barrier(0);
    __builtin_amdgcn_s_barrier();
    __builtin_amdgcn_sched_barrier(0);
    // restage the just-freed buffer with tile t+2 (overlaps kk1 MFMAs)
    if (t + 2 < KT) stage(t + 2, cur);
    __builtin_amdgcn_s_setprio(1);
#pragma unroll
    for (int i = 0; i < 4; ++i)
#pragma unroll
      for (int j = 0; j < 4; ++j)
        acc[i][j] = __builtin_amdgcn_mfma_f32_16x16x32_bf16(
            af[1][i], bfr[1][j], acc[i][j], 0, 0, 0);
    __builtin_amdgcn_s_setprio(0);
    // end of step: tile t+1 must be resident; tile t+2's 6 loads stay in
    // flight across the barrier (counted vmcnt, never 0 mid-loop).
    if (t + 1 < KT) {
      if (t + 2 < KT) asm volatile("s_waitcnt vmcnt(6)" ::: "memory");
      else            asm volatile("s_waitcnt vmcnt(0)" ::: "memory");
      __builtin_amdgcn_sched_barrier(0);
      __builtin_amdgcn_s_barrier();
      __builtin_amdgcn_sched_barrier(0);
    }
  }

  // C/D layout: col = lane&15, row = quad*4 + reg
#pragma unroll
  for (int i = 0; i < 4; ++i) {
    const int mbase = tile_m + wm + i * 16 + quad * 4;
#pragma unroll
    for (int j = 0; j < 4; ++j) {
      const int n  = tile_n + wn + j * 16 + l16;
      const float bv = bias[n];
      const float v0 = acc[i][j][0] + bv, v1 = acc[i][j][1] + bv;
      const float v2 = acc[i][j][2] + bv, v3 = acc[i][j][3] + bv;
      if (OUTBF16) {
        u16* cp = reinterpret_cast<u16*>(Cout) + (size_t)mbase * N + n;
        const uint32_t p01 = pk2(v0, v1), p23 = pk2(v2, v3);
        if (mbase + 0 < Mstore) cp[0]            = (u16)p01;
        if (mbase + 1 < Mstore) cp[(size_t)N]    = (u16)(p01 >> 16);
        if (mbase + 2 < Mstore) cp[(size_t)N*2]  = (u16)p23;
        if (mbase + 3 < Mstore) cp[(size_t)N*3]  = (u16)(p23 >> 16);
      } else {
        float* cp = reinterpret_cast<float*>(Cout) + (size_t)mbase * N + n;
        if (mbase + 0 < Mstore) cp[0]           = v0;
        if (mbase + 1 < Mstore) cp[(size_t)N]   = v1;
        if (mbase + 2 < Mstore) cp[(size_t)N*2] = v2;
        if (mbase + 3 < Mstore) cp[(size_t)N*3] = v3;
      }
    }
  }
}

// ---------------- kv partials + exp-sum partials ---------------------------
// kvpart[bh][split][c][d] = sum_{n in split} exp(k[n,c]) * v[n,d]
// kvsum [bh][split][c]    = sum_{n in split} exp(k[n,c])
// No max subtraction: k ~ N(0,1), |k| small -> exp safe in f32.
__global__ __launch_bounds__(256)
void kv_kernel(const u16* __restrict__ qkv, float* __restrict__ kvpart,
               float* __restrict__ kvsum) {
  const int bh = blockIdx.x, split = blockIdx.y;
  const int b = bh >> 3, h = bh & 7;
  const int n_start = split * 113;
  const int n_end = min(NTOK, n_start + 113);
  const int t = threadIdx.x;
  const int d = t & 63, cq = t >> 6;
  __shared__ float e_s[32 * 64];
  __shared__ float v_s[32 * 64];
  const u16* kbase = qkv + (size_t)(b * NTOK) * QKVN + CDIM + h * CHD;
  const u16* vbase = kbase + CDIM;
  float acc[16];
#pragma unroll
  for (int i = 0; i < 16; ++i) acc[i] = 0.f;
  float s_part = 0.f;   // sum of exp over this thread's staged elems (c = t&63)

  for (int n0 = n_start; n0 < n_end; n0 += 32) {
    const int nc = min(32, n_end - n0);
    __syncthreads();
    for (int i = t; i < nc * 64; i += 256) {
      const int nl = i >> 6, c = i & 63;
      const float e = __expf(bf2f(kbase[(size_t)(n0 + nl) * QKVN + c]));
      e_s[i] = e; s_part += e;
      v_s[i] = bf2f(vbase[(size_t)(n0 + nl) * QKVN + c]);
    }
    __syncthreads();
    for (int nl = 0; nl < nc; ++nl) {
      const float vv = v_s[nl * 64 + d];
#pragma unroll
      for (int i = 0; i < 16; ++i)
        acc[i] += e_s[nl * 64 + cq * 16 + i] * vv;
    }
  }
#pragma unroll
  for (int i = 0; i < 16; ++i) {
    const int c = cq * 16 + i;
    kvpart[(((size_t)bh * KVSPLIT + split) * 64 + c) * 64 + d] = acc[i];
  }
  __syncthreads();
  e_s[t] = s_part;
  __syncthreads();
  if (t < 64)
    kvsum[((size_t)bh * KVSPLIT + split) * 64 + t] =
        e_s[t] + e_s[64 + t] + e_s[128 + t] + e_s[192 + t];
}

// ---------------- reduce partials -> kvT[bh][d][c] bf16 (B-operand layout) -
__global__ __launch_bounds__(256)
void kv_reduce_kernel(const float* __restrict__ kvpart, const float* __restrict__ kvsum,
                      u16* __restrict__ kvT) {
  const int bh = blockIdx.x;
  const int t = threadIdx.x;
  const int d = t & 63, cq = t >> 6;
#pragma unroll
  for (int cc = 0; cc < 16; ++cc) {
    const int c = cq * 16 + cc;
    float s = 0.f, S = 0.f;
#pragma unroll
    for (int sp = 0; sp < KVSPLIT; ++sp) {
      s += kvpart[(((size_t)bh * KVSPLIT + sp) * 64 + c) * 64 + d];
      S += kvsum[((size_t)bh * KVSPLIT + sp) * 64 + c];
    }
    kvT[(size_t)bh * 4096 + d * 64 + c] = f2bf(s / S);
  }
}

// ---------------- depthwise conv + EV fuse ---------------------------------
template <int KS>
__device__ __forceinline__ void conv_head(
    const u16* __restrict__ qkv, const float* __restrict__ wgt,
    const float* __restrict__ bias, int b, int head, int hh, int yt,
    u16* __restrict__ evbuf, u16* __restrict__ ls) {
  constexpr int PAD = KS / 2;
  constexpr int RIN = 4 + 2 * PAD;
  const int t = threadIdx.x;
  const int y0 = yt * 4;
  const u16* vimg = qkv + (size_t)(b * NTOK + 1) * QKVN + 2 * CDIM + head * 64;
  const int c8 = (t & 7) * 8;
  for (int pi = t >> 3; pi < RIN * 28; pi += 32) {
    const int ry = pi / 28, rx = pi - ry * 28;
    const int yy = y0 - PAD + ry;
    uint4 val = {0, 0, 0, 0};
    if (yy >= 0 && yy < 28)
      val = *reinterpret_cast<const uint4*>(vimg + (size_t)(yy * 28 + rx) * QKVN + c8);
    *reinterpret_cast<uint4*>(ls + pi * 64 + c8) = val;
  }
  __syncthreads();
  const int d = t & 63, yl = t >> 6;
  float wr[KS * KS];
  const float* wp = wgt + (hh * 64 + d) * KS * KS;
#pragma unroll
  for (int i = 0; i < KS * KS; ++i) wr[i] = wp[i];
  const float bv = bias[hh * 64 + d];
  float acc[28];
#pragma unroll
  for (int x = 0; x < 28; ++x) acc[x] = bv;
#pragma unroll
  for (int xx = 0; xx < 28; ++xx) {
    float col[KS];
#pragma unroll
    for (int r = 0; r < KS; ++r)
      col[r] = bf2f(ls[((yl + r) * 28 + xx) * 64 + d]);
#pragma unroll
    for (int j = 0; j < KS; ++j) {
      const int x = xx + PAD - j;
      if (x >= 0 && x < 28) {
#pragma unroll
        for (int r = 0; r < KS; ++r)
          acc[x] += col[r] * wr[r * KS + j];
      }
    }
  }
  const int p0 = (y0 + yl) * 28;
  const u16* qrow = qkv + (size_t)(b * NTOK + 1 + p0) * QKVN + head * 64 + d;
  u16* obase = evbuf + (((size_t)(b * 8 + head)) * IMGHW + p0) * 64 + d;
#pragma unroll
  for (int x = 0; x < 28; ++x) {
    const float ev = acc[x] * bf2f(qrow[(size_t)x * QKVN]);
    obase[(size_t)x * 64] = f2bf(ev);
  }
}

__global__ __launch_bounds__(256)
void conv_all_kernel(const u16* __restrict__ qkv,
                     const float* __restrict__ w3, const float* __restrict__ b3,
                     const float* __restrict__ w5, const float* __restrict__ b5,
                     const float* __restrict__ w7, const float* __restrict__ b7,
                     u16* __restrict__ evbuf) {
  __shared__ __align__(16) u16 ls[10 * 28 * 64];
  const int b = blockIdx.x, h = blockIdx.y, yt = blockIdx.z;
  if (h < 2)      conv_head<3>(qkv, w3, b3, b, h, h,     yt, evbuf, ls);
  else if (h < 5) conv_head<5>(qkv, w5, b5, b, h, h - 2, yt, evbuf, ls);
  else            conv_head<7>(qkv, w7, b7, b, h, h - 5, yt, evbuf, ls);
}

// ---------------- combine: factor_att via MFMA + CRPE ----------------------
__global__ __launch_bounds__(256)
void combine_kernel(const u16* __restrict__ qkv, const u16* __restrict__ kvT,
                    const u16* __restrict__ evbuf, u16* __restrict__ attn) {
  const int bh = blockIdx.x;
  const int b = bh >> 3, h = bh & 7;
  const int wave = threadIdx.x >> 6, lane = threadIdx.x & 63;
  const int quad = lane >> 4, l16 = lane & 15;
  const int tokbase = blockIdx.y * 256 + wave * 64;

  const u16* kvb = kvT + (size_t)bh * 4096;
  bf16x8 bfr[4][2];
#pragma unroll
  for (int j = 0; j < 4; ++j)
#pragma unroll
    for (int kk = 0; kk < 2; ++kk)
      bfr[j][kk] = *reinterpret_cast<const bf16x8*>(
          &kvb[(j * 16 + l16) * 64 + kk * 32 + quad * 8]);

  bf16x8 af[4][2];
#pragma unroll
  for (int i = 0; i < 4; ++i) {
    const int tok = min(tokbase + i * 16 + l16, NTOK - 1);
    const u16* qrow = qkv + (size_t)(b * NTOK + tok) * QKVN + h * CHD;
    af[i][0] = *reinterpret_cast<const bf16x8*>(&qrow[quad * 8]);
    af[i][1] = *reinterpret_cast<const bf16x8*>(&qrow[32 + quad * 8]);
  }

  f32x4 acc[4][4] = {};
#pragma unroll
  for (int kk = 0; kk < 2; ++kk)
#pragma unroll
    for (int i = 0; i < 4; ++i)
#pragma unroll
      for (int j = 0; j < 4; ++j)
        acc[i][j] = __builtin_amdgcn_mfma_f32_16x16x32_bf16(af[i][kk], bfr[j][kk], acc[i][j], 0, 0, 0);

  const float scale = 0.125f;
  const u16* evb = evbuf + (size_t)bh * IMGHW * 64;
#pragma unroll
  for (int i = 0; i < 4; ++i) {
#pragma unroll
    for (int r = 0; r < 4; ++r) {
      const int tok = tokbase + i * 16 + quad * 4 + r;
      if (tok < NTOK) {
#pragma unroll
        for (int j = 0; j < 4; ++j) {
          const int d = j * 16 + l16;
          float out = scale * acc[i][j][r];
          if (tok > 0) out += bf2f(evb[(size_t)(tok - 1) * 64 + d]);
          attn[(size_t)(b * NTOK + tok) * CDIM + h * CHD + d] = f2bf(out);
        }
      }
    }
  }
}

// ---------------- launch ---------------------------------------------------
extern "C" void kernel_launch(void* const* d_in, const int* in_sizes, int n_in,
                              void* d_out, int out_size, void* d_ws, size_t ws_size,
                              hipStream_t stream) {
  const float* x      = (const float*)d_in[0];
  const float* qkv_w  = (const float*)d_in[1];
  const float* qkv_b  = (const float*)d_in[2];
  const float* proj_w = (const float*)d_in[3];
  const float* proj_b = (const float*)d_in[4];
  const float* w3 = (const float*)d_in[5];
  const float* b3 = (const float*)d_in[6];
  const float* w5 = (const float*)d_in[7];
  const float* b5 = (const float*)d_in[8];
  const float* w7 = (const float*)d_in[9];
  const float* b7 = (const float*)d_in[10];
  float* out = (float*)d_out;

  char* p = (char*)d_ws;
  u16* xb    = (u16*)p;   p += (size_t)MPAD * CDIM * 2;
  u16* wqb   = (u16*)p;   p += (size_t)QKVN * CDIM * 2;
  u16* wpb   = (u16*)p;   p += (size_t)CDIM * CDIM * 2;
  u16* qkvb  = (u16*)p;   p += (size_t)MPAD * QKVN * 2;
  float* kvsum = (float*)p; p += (size_t)256 * KVSPLIT * 64 * 4;
  u16* kvT   = (u16*)p;   p += (size_t)256 * 64 * 64 * 2;
  // kvpart (f32, 29.4 MB) and evbuf (bf16, 25.7 MB) share one region:
  // kvpart dead after kv_reduce; conv writes evbuf afterwards.
  char* shared_region = p;
  float* kvpart = (float*)shared_region;
  u16*   evbuf  = (u16*)shared_region;
  p += (size_t)256 * KVSPLIT * 64 * 64 * 4;
  u16* attn  = (u16*)p;   p += (size_t)MPAD * CDIM * 2;

  // 1. casts (single launch)
  {
    const int total = MROWS * CDIM / 4 + QKVN * CDIM / 4 + CDIM * CDIM / 4;
    casts_kernel<<<(total + 255) / 256, 256, 0, stream>>>(x, xb, qkv_w, wqb, proj_w, wpb);
  }
  // 2. qkv = x @ qkv_w^T + qkv_b  (bf16 out). nMt=99, nNt=12, XCD-banded grid.
  gemm_bt<1><<<13 * 8 * 12, 512, 0, stream>>>(xb, wqb, qkv_b, qkvb,
                                              MPAD, QKVN, CDIM, 99, 12);
  // 3. kv partials + exp-sums
  kv_kernel<<<dim3(256, KVSPLIT), 256, 0, stream>>>(qkvb, kvpart, kvsum);
  kv_reduce_kernel<<<256, 256, 0, stream>>>(kvpart, kvsum, kvT);
  // 4. depthwise convs + EV fuse
  conv_all_kernel<<<dim3(BATCH, HEADS, 7), 256, 0, stream>>>(
      qkvb, w3, b3, w5, b5, w7, b7, evbuf);
  // 5. factor_att + CRPE -> attn (bf16)
  combine_kernel<<<dim3(256, 4), 256, 0, stream>>>(qkvb, kvT, evbuf, attn);
  // 6. out = attn @ proj_w^T + proj_b  (f32 out). nMt=99, nNt=4.
  gemm_bt<0><<<13 * 8 * 4, 512, 0, stream>>>(attn, wpb, proj_b, out,
                                             MROWS, CDIM, CDIM, 99, 4);
}

// Round 3
// 327.251 us; speedup vs baseline: 1.0865x; 1.0514x over previous
//
#include <hip/hip_runtime.h>
#include <cstdint>
#include <cstddef>

// CoaT factorized attention block, MI355X/gfx950.
// R8: post-mortem of R6/R7 — in-block pipelines at 96 KB LDS lose more from
// 3->1 blk/CU residency than they gain. R8 keeps R5's 48 KB / 3 blk/CU and
// adds the double buffer by halving BK to 32: lsA[2][256x32]+lsB[2][128x32]
// = 48 KB. Simple 2-phase schedule (stage t+1 before computing t, one
// __syncthreads per K-tile; barrier count unchanged vs R5). New XOR swizzle
// for 64B rows: physical chunk = logical ^ ((row>>1)&3) -> conflict-free
// b128 fragment reads (8 lanes per granule class, distinct granules).

typedef unsigned short u16;

#define HEADS 8
#define CHD   64
#define CDIM  512
#define NTOK  785
#define BATCH 32
#define MROWS (BATCH * NTOK)   // 25120
#define MPAD  25344            // 99 * 256
#define QKVN  1536
#define IMGHW 784
#define KVSPLIT 7

typedef float  f32x4  __attribute__((ext_vector_type(4)));
typedef __bf16 bf16x8 __attribute__((ext_vector_type(8)));

__device__ __forceinline__ u16 f2bf(float f) {
  union { float f; uint32_t u; } x; x.f = f;
  uint32_t r = x.u + 0x7fffu + ((x.u >> 16) & 1u);  // RNE
  return (u16)(r >> 16);
}
__device__ __forceinline__ float bf2f(u16 u) {
  union { uint32_t u; float f; } x; x.u = ((uint32_t)u) << 16;
  return x.f;
}
// packed f32x2 -> bf16x2 (low = a, high = b)
__device__ __forceinline__ uint32_t pk2(float a, float b) {
#if __has_builtin(__builtin_amdgcn_cvt_pk_bf16_f32)
  auto v = __builtin_amdgcn_cvt_pk_bf16_f32(a, b);
  union { decltype(v) v2; uint32_t u; } cv; cv.v2 = v; return cv.u;
#else
  return (uint32_t)f2bf(a) | ((uint32_t)f2bf(b) << 16);
#endif
}

// ---------------- merged f32 -> bf16 casts (x, qkv_w, proj_w) --------------
__global__ __launch_bounds__(256)
void casts_kernel(const float* __restrict__ x, u16* __restrict__ xb,
                  const float* __restrict__ w1, u16* __restrict__ w1b,
                  const float* __restrict__ w2, u16* __restrict__ w2b) {
  const int N1 = MROWS * CDIM / 4, N2 = QKVN * CDIM / 4, N3 = CDIM * CDIM / 4;
  int i = blockIdx.x * 256 + threadIdx.x;
  const float* src; u16* dst;
  if (i < N1)           { src = x;  dst = xb;  }
  else if (i < N1 + N2) { i -= N1;  src = w1; dst = w1b; }
  else if (i < N1 + N2 + N3) { i -= N1 + N2; src = w2; dst = w2b; }
  else return;
  float4 v = reinterpret_cast<const float4*>(src)[i];
  uint2 o; o.x = pk2(v.x, v.y); o.y = pk2(v.z, v.w);
  reinterpret_cast<uint2*>(dst)[i] = o;
}

// ---------------- async global->LDS, 16B per lane --------------------------
__device__ __forceinline__ void gld_lds16(const u16* g, u16* l) {
  __builtin_amdgcn_global_load_lds((__attribute__((address_space(1))) void*)g,
                                   (__attribute__((address_space(3))) void*)l,
                                   16, 0, 0);
}

// ---------------- bf16 MFMA GEMM, C = A @ W^T + bias -----------------------
// 256x128 tile, 512 threads = 8 waves in 4(row)x2(col); per wave 4x4 of
// 16x16x32 MFMA, one K-chunk of 32 per tile.
// BK=32 double-buffered (48 KB total -> 3 blocks/CU), 2-phase schedule:
//   prologue: stage(tile0 -> buf0); __syncthreads
//   iter t:   stage(t+1 -> buf[cur^1]);   // async, drains at end-of-iter
//             ds_read 8 frags buf[cur]; 16 MFMA; __syncthreads
// Swizzle (64B rows, 4 chunks of 16B): physical chunk = logical ^ ((row>>1)&3).
// Staging keeps linear LDS dest (tid*16B); source col pre-swizzled:
// scol = ((tid&3) ^ ((tid>>3)&3))*8  (row = s*128 + (tid>>2); s*64 drops out).
// Fragment read: pch = quad ^ ((l16>>1)&3) -> logical chunk = quad. 64-lane
// b128 read spreads 8 lanes per granule class, distinct granules: conflict-free.
// Grid: flat 1D, XCD-banded, N-fastest (xcd = flat&7).
template <int OUTBF16>
__global__ __launch_bounds__(512)
void gemm_bt(const u16* __restrict__ A, const u16* __restrict__ W,
             const float* __restrict__ bias, void* __restrict__ Cout,
             int Mstore, int N, int K, int nMt, int nNt) {
  __shared__ __align__(16) u16 lsA[2][256 * 32];   // 32 KB
  __shared__ __align__(16) u16 lsB[2][128 * 32];   // 16 KB
  const int flat = blockIdx.x;
  const int xcd = flat & 7, idx = flat >> 3;
  const int nt = idx % nNt;
  const int mt = (idx / nNt) * 8 + xcd;
  if (mt >= nMt) return;
  const int tile_m = mt * 256, tile_n = nt * 128;

  const int tid  = threadIdx.x;
  const int wave = tid >> 6, lane = tid & 63;
  const int quad = lane >> 4, l16 = lane & 15;
  const int wm = (wave & 3) * 64, wn = (wave >> 2) * 64;

  // staging: thread covers row s*128 + (tid>>2), physical chunk (tid&3);
  // loads logical chunk (tid&3) ^ ((tid>>3)&3). LDS dest linear: tid*8 elems.
  const int srow = tid >> 2;                               // 0..127
  const int scol = ((tid & 3) ^ ((tid >> 3) & 3)) * 8;
  const int ldst = tid * 8;

  auto stage = [&](int kt, int buf) {
    const int kc = kt * 32 + scol;
#pragma unroll
    for (int s = 0; s < 2; ++s)
      gld_lds16(A + (size_t)(tile_m + s * 128 + srow) * K + kc,
                &lsA[buf][s * 4096 + ldst]);
    gld_lds16(W + (size_t)(tile_n + srow) * K + kc, &lsB[buf][ldst]);
  };

  f32x4 acc[4][4] = {};

  // prologue: tile 0 -> buffer 0 (syncthreads drains vmcnt)
  stage(0, 0);
  __syncthreads();

  const int KT = K >> 5;                 // 16 at both call sites
  const int pch = (quad ^ ((l16 >> 1) & 3)) * 8;   // physical chunk offset
#pragma unroll 2
  for (int t = 0; t < KT; ++t) {
    const int cur = t & 1;
    // issue next tile's async loads first: they fly under ds_read + MFMA
    if (t + 1 < KT) stage(t + 1, cur ^ 1);
    bf16x8 af[4], bfr[4];
#pragma unroll
    for (int i = 0; i < 4; ++i) {
      af[i]  = *reinterpret_cast<const bf16x8*>(
          &lsA[cur][(wm + i * 16 + l16) * 32 + pch]);
      bfr[i] = *reinterpret_cast<const bf16x8*>(
          &lsB[cur][(wn + i * 16 + l16) * 32 + pch]);
    }
#pragma unroll
    for (int i = 0; i < 4; ++i)
#pragma unroll
      for (int j = 0; j < 4; ++j)
        acc[i][j] = __builtin_amdgcn_mfma_f32_16x16x32_bf16(
            af[i], bfr[j], acc[i][j], 0, 0, 0);
    // one barrier per K-tile: drains vmcnt (tile t+1 resident for next iter)
    // and lgkmcnt, and gates buffer reuse across waves.
    __syncthreads();
  }

  // C/D layout: col = lane&15, row = quad*4 + reg
#pragma unroll
  for (int i = 0; i < 4; ++i) {
    const int mbase = tile_m + wm + i * 16 + quad * 4;
#pragma unroll
    for (int j = 0; j < 4; ++j) {
      const int n  = tile_n + wn + j * 16 + l16;
      const float bv = bias[n];
      const float v0 = acc[i][j][0] + bv, v1 = acc[i][j][1] + bv;
      const float v2 = acc[i][j][2] + bv, v3 = acc[i][j][3] + bv;
      if (OUTBF16) {
        u16* cp = reinterpret_cast<u16*>(Cout) + (size_t)mbase * N + n;
        const uint32_t p01 = pk2(v0, v1), p23 = pk2(v2, v3);
        if (mbase + 0 < Mstore) cp[0]            = (u16)p01;
        if (mbase + 1 < Mstore) cp[(size_t)N]    = (u16)(p01 >> 16);
        if (mbase + 2 < Mstore) cp[(size_t)N*2]  = (u16)p23;
        if (mbase + 3 < Mstore) cp[(size_t)N*3]  = (u16)(p23 >> 16);
      } else {
        float* cp = reinterpret_cast<float*>(Cout) + (size_t)mbase * N + n;
        if (mbase + 0 < Mstore) cp[0]           = v0;
        if (mbase + 1 < Mstore) cp[(size_t)N]   = v1;
        if (mbase + 2 < Mstore) cp[(size_t)N*2] = v2;
        if (mbase + 3 < Mstore) cp[(size_t)N*3] = v3;
      }
    }
  }
}

// ---------------- kv partials + exp-sum partials ---------------------------
// kvpart[bh][split][c][d] = sum_{n in split} exp(k[n,c]) * v[n,d]
// kvsum [bh][split][c]    = sum_{n in split} exp(k[n,c])
// No max subtraction: k ~ N(0,1), |k| small -> exp safe in f32.
__global__ __launch_bounds__(256)
void kv_kernel(const u16* __restrict__ qkv, float* __restrict__ kvpart,
               float* __restrict__ kvsum) {
  const int bh = blockIdx.x, split = blockIdx.y;
  const int b = bh >> 3, h = bh & 7;
  const int n_start = split * 113;
  const int n_end = min(NTOK, n_start + 113);
  const int t = threadIdx.x;
  const int d = t & 63, cq = t >> 6;
  __shared__ float e_s[32 * 64];
  __shared__ float v_s[32 * 64];
  const u16* kbase = qkv + (size_t)(b * NTOK) * QKVN + CDIM + h * CHD;
  const u16* vbase = kbase + CDIM;
  float acc[16];
#pragma unroll
  for (int i = 0; i < 16; ++i) acc[i] = 0.f;
  float s_part = 0.f;   // sum of exp over this thread's staged elems (c = t&63)

  for (int n0 = n_start; n0 < n_end; n0 += 32) {
    const int nc = min(32, n_end - n0);
    __syncthreads();
    for (int i = t; i < nc * 64; i += 256) {
      const int nl = i >> 6, c = i & 63;
      const float e = __expf(bf2f(kbase[(size_t)(n0 + nl) * QKVN + c]));
      e_s[i] = e; s_part += e;
      v_s[i] = bf2f(vbase[(size_t)(n0 + nl) * QKVN + c]);
    }
    __syncthreads();
    for (int nl = 0; nl < nc; ++nl) {
      const float vv = v_s[nl * 64 + d];
#pragma unroll
      for (int i = 0; i < 16; ++i)
        acc[i] += e_s[nl * 64 + cq * 16 + i] * vv;
    }
  }
#pragma unroll
  for (int i = 0; i < 16; ++i) {
    const int c = cq * 16 + i;
    kvpart[(((size_t)bh * KVSPLIT + split) * 64 + c) * 64 + d] = acc[i];
  }
  __syncthreads();
  e_s[t] = s_part;
  __syncthreads();
  if (t < 64)
    kvsum[((size_t)bh * KVSPLIT + split) * 64 + t] =
        e_s[t] + e_s[64 + t] + e_s[128 + t] + e_s[192 + t];
}

// ---------------- reduce partials -> kvT[bh][d][c] bf16 (B-operand layout) -
__global__ __launch_bounds__(256)
void kv_reduce_kernel(const float* __restrict__ kvpart, const float* __restrict__ kvsum,
                      u16* __restrict__ kvT) {
  const int bh = blockIdx.x;
  const int t = threadIdx.x;
  const int d = t & 63, cq = t >> 6;
#pragma unroll
  for (int cc = 0; cc < 16; ++cc) {
    const int c = cq * 16 + cc;
    float s = 0.f, S = 0.f;
#pragma unroll
    for (int sp = 0; sp < KVSPLIT; ++sp) {
      s += kvpart[(((size_t)bh * KVSPLIT + sp) * 64 + c) * 64 + d];
      S += kvsum[((size_t)bh * KVSPLIT + sp) * 64 + c];
    }
    kvT[(size_t)bh * 4096 + d * 64 + c] = f2bf(s / S);
  }
}

// ---------------- depthwise conv + EV fuse ---------------------------------
template <int KS>
__device__ __forceinline__ void conv_head(
    const u16* __restrict__ qkv, const float* __restrict__ wgt,
    const float* __restrict__ bias, int b, int head, int hh, int yt,
    u16* __restrict__ evbuf, u16* __restrict__ ls) {
  constexpr int PAD = KS / 2;
  constexpr int RIN = 4 + 2 * PAD;
  const int t = threadIdx.x;
  const int y0 = yt * 4;
  const u16* vimg = qkv + (size_t)(b * NTOK + 1) * QKVN + 2 * CDIM + head * 64;
  const int c8 = (t & 7) * 8;
  for (int pi = t >> 3; pi < RIN * 28; pi += 32) {
    const int ry = pi / 28, rx = pi - ry * 28;
    const int yy = y0 - PAD + ry;
    uint4 val = {0, 0, 0, 0};
    if (yy >= 0 && yy < 28)
      val = *reinterpret_cast<const uint4*>(vimg + (size_t)(yy * 28 + rx) * QKVN + c8);
    *reinterpret_cast<uint4*>(ls + pi * 64 + c8) = val;
  }
  __syncthreads();
  const int d = t & 63, yl = t >> 6;
  float wr[KS * KS];
  const float* wp = wgt + (hh * 64 + d) * KS * KS;
#pragma unroll
  for (int i = 0; i < KS * KS; ++i) wr[i] = wp[i];
  const float bv = bias[hh * 64 + d];
  float acc[28];
#pragma unroll
  for (int x = 0; x < 28; ++x) acc[x] = bv;
#pragma unroll
  for (int xx = 0; xx < 28; ++xx) {
    float col[KS];
#pragma unroll
    for (int r = 0; r < KS; ++r)
      col[r] = bf2f(ls[((yl + r) * 28 + xx) * 64 + d]);
#pragma unroll
    for (int j = 0; j < KS; ++j) {
      const int x = xx + PAD - j;
      if (x >= 0 && x < 28) {
#pragma unroll
        for (int r = 0; r < KS; ++r)
          acc[x] += col[r] * wr[r * KS + j];
      }
    }
  }
  const int p0 = (y0 + yl) * 28;
  const u16* qrow = qkv + (size_t)(b * NTOK + 1 + p0) * QKVN + head * 64 + d;
  u16* obase = evbuf + (((size_t)(b * 8 + head)) * IMGHW + p0) * 64 + d;
#pragma unroll
  for (int x = 0; x < 28; ++x) {
    const float ev = acc[x] * bf2f(qrow[(size_t)x * QKVN]);
    obase[(size_t)x * 64] = f2bf(ev);
  }
}

__global__ __launch_bounds__(256)
void conv_all_kernel(const u16* __restrict__ qkv,
                     const float* __restrict__ w3, const float* __restrict__ b3,
                     const float* __restrict__ w5, const float* __restrict__ b5,
                     const float* __restrict__ w7, const float* __restrict__ b7,
                     u16* __restrict__ evbuf) {
  __shared__ __align__(16) u16 ls[10 * 28 * 64];
  const int b = blockIdx.x, h = blockIdx.y, yt = blockIdx.z;
  if (h < 2)      conv_head<3>(qkv, w3, b3, b, h, h,     yt, evbuf, ls);
  else if (h < 5) conv_head<5>(qkv, w5, b5, b, h, h - 2, yt, evbuf, ls);
  else            conv_head<7>(qkv, w7, b7, b, h, h - 5, yt, evbuf, ls);
}

// ---------------- combine: factor_att via MFMA + CRPE ----------------------
__global__ __launch_bounds__(256)
void combine_kernel(const u16* __restrict__ qkv, const u16* __restrict__ kvT,
                    const u16* __restrict__ evbuf, u16* __restrict__ attn) {
  const int bh = blockIdx.x;
  const int b = bh >> 3, h = bh & 7;
  const int wave = threadIdx.x >> 6, lane = threadIdx.x & 63;
  const int quad = lane >> 4, l16 = lane & 15;
  const int tokbase = blockIdx.y * 256 + wave * 64;

  const u16* kvb = kvT + (size_t)bh * 4096;
  bf16x8 bfr[4][2];
#pragma unroll
  for (int j = 0; j < 4; ++j)
#pragma unroll
    for (int kk = 0; kk < 2; ++kk)
      bfr[j][kk] = *reinterpret_cast<const bf16x8*>(
          &kvb[(j * 16 + l16) * 64 + kk * 32 + quad * 8]);

  bf16x8 af[4][2];
#pragma unroll
  for (int i = 0; i < 4; ++i) {
    const int tok = min(tokbase + i * 16 + l16, NTOK - 1);
    const u16* qrow = qkv + (size_t)(b * NTOK + tok) * QKVN + h * CHD;
    af[i][0] = *reinterpret_cast<const bf16x8*>(&qrow[quad * 8]);
    af[i][1] = *reinterpret_cast<const bf16x8*>(&qrow[32 + quad * 8]);
  }

  f32x4 acc[4][4] = {};
#pragma unroll
  for (int kk = 0; kk < 2; ++kk)
#pragma unroll
    for (int i = 0; i < 4; ++i)
#pragma unroll
      for (int j = 0; j < 4; ++j)
        acc[i][j] = __builtin_amdgcn_mfma_f32_16x16x32_bf16(af[i][kk], bfr[j][kk], acc[i][j], 0, 0, 0);

  const float scale = 0.125f;
  const u16* evb = evbuf + (size_t)bh * IMGHW * 64;
#pragma unroll
  for (int i = 0; i < 4; ++i) {
#pragma unroll
    for (int r = 0; r < 4; ++r) {
      const int tok = tokbase + i * 16 + quad * 4 + r;
      if (tok < NTOK) {
#pragma unroll
        for (int j = 0; j < 4; ++j) {
          const int d = j * 16 + l16;
          float out = scale * acc[i][j][r];
          if (tok > 0) out += bf2f(evb[(size_t)(tok - 1) * 64 + d]);
          attn[(size_t)(b * NTOK + tok) * CDIM + h * CHD + d] = f2bf(out);
        }
      }
    }
  }
}

// ---------------- launch ---------------------------------------------------
extern "C" void kernel_launch(void* const* d_in, const int* in_sizes, int n_in,
                              void* d_out, int out_size, void* d_ws, size_t ws_size,
                              hipStream_t stream) {
  const float* x      = (const float*)d_in[0];
  const float* qkv_w  = (const float*)d_in[1];
  const float* qkv_b  = (const float*)d_in[2];
  const float* proj_w = (const float*)d_in[3];
  const float* proj_b = (const float*)d_in[4];
  const float* w3 = (const float*)d_in[5];
  const float* b3 = (const float*)d_in[6];
  const float* w5 = (const float*)d_in[7];
  const float* b5 = (const float*)d_in[8];
  const float* w7 = (const float*)d_in[9];
  const float* b7 = (const float*)d_in[10];
  float* out = (float*)d_out;

  char* p = (char*)d_ws;
  u16* xb    = (u16*)p;   p += (size_t)MPAD * CDIM * 2;
  u16* wqb   = (u16*)p;   p += (size_t)QKVN * CDIM * 2;
  u16* wpb   = (u16*)p;   p += (size_t)CDIM * CDIM * 2;
  u16* qkvb  = (u16*)p;   p += (size_t)MPAD * QKVN * 2;
  float* kvsum = (float*)p; p += (size_t)256 * KVSPLIT * 64 * 4;
  u16* kvT   = (u16*)p;   p += (size_t)256 * 64 * 64 * 2;
  // kvpart (f32, 29.4 MB) and evbuf (bf16, 25.7 MB) share one region:
  // kvpart dead after kv_reduce; conv writes evbuf afterwards.
  char* shared_region = p;
  float* kvpart = (float*)shared_region;
  u16*   evbuf  = (u16*)shared_region;
  p += (size_t)256 * KVSPLIT * 64 * 64 * 4;
  u16* attn  = (u16*)p;   p += (size_t)MPAD * CDIM * 2;

  // 1. casts (single launch)
  {
    const int total = MROWS * CDIM / 4 + QKVN * CDIM / 4 + CDIM * CDIM / 4;
    casts_kernel<<<(total + 255) / 256, 256, 0, stream>>>(x, xb, qkv_w, wqb, proj_w, wpb);
  }
  // 2. qkv = x @ qkv_w^T + qkv_b  (bf16 out). nMt=99, nNt=12, XCD-banded grid.
  gemm_bt<1><<<13 * 8 * 12, 512, 0, stream>>>(xb, wqb, qkv_b, qkvb,
                                              MPAD, QKVN, CDIM, 99, 12);
  // 3. kv partials + exp-sums
  kv_kernel<<<dim3(256, KVSPLIT), 256, 0, stream>>>(qkvb, kvpart, kvsum);
  kv_reduce_kernel<<<256, 256, 0, stream>>>(kvpart, kvsum, kvT);
  // 4. depthwise convs + EV fuse
  conv_all_kernel<<<dim3(BATCH, HEADS, 7), 256, 0, stream>>>(
      qkvb, w3, b3, w5, b5, w7, b7, evbuf);
  // 5. factor_att + CRPE -> attn (bf16)
  combine_kernel<<<dim3(256, 4), 256, 0, stream>>>(qkvb, kvT, evbuf, attn);
  // 6. out = attn @ proj_w^T + proj_b  (f32 out). nMt=99, nNt=4.
  gemm_bt<0><<<13 * 8 * 4, 512, 0, stream>>>(attn, wpb, proj_b, out,
                                             MROWS, CDIM, CDIM, 99, 4);
}

// Round 4
// 313.068 us; speedup vs baseline: 1.1357x; 1.0453x over previous
//
#include <hip/hip_runtime.h>
#include <cstdint>
#include <cstddef>

// CoaT factorized attention block, MI355X/gfx950.
// R9: GEMM frozen (R8 version). Attack the non-GEMM ~256 us:
//  - kv: vectorized K/V staging (uint2 loads, float4 LDS), float4 e_s reads,
//    exp-sum reduction reworked for 4-c-per-thread ownership.
//  - combine: two-round LDS-transpose epilogue -> vectorized 16B evbuf reads
//    and 16B attn stores (was 64+64 scalar 2B ops/thread). f32 LDS keeps
//    single-rounding (bit-identical math).
//  - conv: weights staged to LDS coalesced (was 49 strided lane loads).
//  - kv+conv merged into one launch; evbuf moved to xb region (dead after
//    gemm1) so kvpart no longer aliases evbuf.

typedef unsigned short u16;

#define HEADS 8
#define CHD   64
#define CDIM  512
#define NTOK  785
#define BATCH 32
#define MROWS (BATCH * NTOK)   // 25120
#define MPAD  25344            // 99 * 256
#define QKVN  1536
#define IMGHW 784
#define KVSPLIT 7

typedef float  f32x4  __attribute__((ext_vector_type(4)));
typedef __bf16 bf16x8 __attribute__((ext_vector_type(8)));

__device__ __forceinline__ u16 f2bf(float f) {
  union { float f; uint32_t u; } x; x.f = f;
  uint32_t r = x.u + 0x7fffu + ((x.u >> 16) & 1u);  // RNE
  return (u16)(r >> 16);
}
__device__ __forceinline__ float bf2f(u16 u) {
  union { uint32_t u; float f; } x; x.u = ((uint32_t)u) << 16;
  return x.f;
}
__device__ __forceinline__ float bflo(uint32_t u) { return bf2f((u16)(u & 0xffffu)); }
__device__ __forceinline__ float bfhi(uint32_t u) { return bf2f((u16)(u >> 16)); }
// packed f32x2 -> bf16x2 (low = a, high = b)
__device__ __forceinline__ uint32_t pk2(float a, float b) {
#if __has_builtin(__builtin_amdgcn_cvt_pk_bf16_f32)
  auto v = __builtin_amdgcn_cvt_pk_bf16_f32(a, b);
  union { decltype(v) v2; uint32_t u; } cv; cv.v2 = v; return cv.u;
#else
  return (uint32_t)f2bf(a) | ((uint32_t)f2bf(b) << 16);
#endif
}

// ---------------- merged f32 -> bf16 casts (x, qkv_w, proj_w) --------------
__global__ __launch_bounds__(256)
void casts_kernel(const float* __restrict__ x, u16* __restrict__ xb,
                  const float* __restrict__ w1, u16* __restrict__ w1b,
                  const float* __restrict__ w2, u16* __restrict__ w2b) {
  const int N1 = MROWS * CDIM / 4, N2 = QKVN * CDIM / 4, N3 = CDIM * CDIM / 4;
  int i = blockIdx.x * 256 + threadIdx.x;
  const float* src; u16* dst;
  if (i < N1)           { src = x;  dst = xb;  }
  else if (i < N1 + N2) { i -= N1;  src = w1; dst = w1b; }
  else if (i < N1 + N2 + N3) { i -= N1 + N2; src = w2; dst = w2b; }
  else return;
  float4 v = reinterpret_cast<const float4*>(src)[i];
  uint2 o; o.x = pk2(v.x, v.y); o.y = pk2(v.z, v.w);
  reinterpret_cast<uint2*>(dst)[i] = o;
}

// ---------------- async global->LDS, 16B per lane --------------------------
__device__ __forceinline__ void gld_lds16(const u16* g, u16* l) {
  __builtin_amdgcn_global_load_lds((__attribute__((address_space(1))) void*)g,
                                   (__attribute__((address_space(3))) void*)l,
                                   16, 0, 0);
}

// ---------------- bf16 MFMA GEMM, C = A @ W^T + bias (R8, frozen) ----------
template <int OUTBF16>
__global__ __launch_bounds__(512)
void gemm_bt(const u16* __restrict__ A, const u16* __restrict__ W,
             const float* __restrict__ bias, void* __restrict__ Cout,
             int Mstore, int N, int K, int nMt, int nNt) {
  __shared__ __align__(16) u16 lsA[2][256 * 32];   // 32 KB
  __shared__ __align__(16) u16 lsB[2][128 * 32];   // 16 KB
  const int flat = blockIdx.x;
  const int xcd = flat & 7, idx = flat >> 3;
  const int nt = idx % nNt;
  const int mt = (idx / nNt) * 8 + xcd;
  if (mt >= nMt) return;
  const int tile_m = mt * 256, tile_n = nt * 128;

  const int tid  = threadIdx.x;
  const int wave = tid >> 6, lane = tid & 63;
  const int quad = lane >> 4, l16 = lane & 15;
  const int wm = (wave & 3) * 64, wn = (wave >> 2) * 64;

  const int srow = tid >> 2;                               // 0..127
  const int scol = ((tid & 3) ^ ((tid >> 3) & 3)) * 8;
  const int ldst = tid * 8;

  auto stage = [&](int kt, int buf) {
    const int kc = kt * 32 + scol;
#pragma unroll
    for (int s = 0; s < 2; ++s)
      gld_lds16(A + (size_t)(tile_m + s * 128 + srow) * K + kc,
                &lsA[buf][s * 4096 + ldst]);
    gld_lds16(W + (size_t)(tile_n + srow) * K + kc, &lsB[buf][ldst]);
  };

  f32x4 acc[4][4] = {};

  stage(0, 0);
  __syncthreads();

  const int KT = K >> 5;                 // 16 at both call sites
  const int pch = (quad ^ ((l16 >> 1) & 3)) * 8;   // physical chunk offset
#pragma unroll 2
  for (int t = 0; t < KT; ++t) {
    const int cur = t & 1;
    if (t + 1 < KT) stage(t + 1, cur ^ 1);
    bf16x8 af[4], bfr[4];
#pragma unroll
    for (int i = 0; i < 4; ++i) {
      af[i]  = *reinterpret_cast<const bf16x8*>(
          &lsA[cur][(wm + i * 16 + l16) * 32 + pch]);
      bfr[i] = *reinterpret_cast<const bf16x8*>(
          &lsB[cur][(wn + i * 16 + l16) * 32 + pch]);
    }
#pragma unroll
    for (int i = 0; i < 4; ++i)
#pragma unroll
      for (int j = 0; j < 4; ++j)
        acc[i][j] = __builtin_amdgcn_mfma_f32_16x16x32_bf16(
            af[i], bfr[j], acc[i][j], 0, 0, 0);
    __syncthreads();
  }

  // C/D layout: col = lane&15, row = quad*4 + reg
#pragma unroll
  for (int i = 0; i < 4; ++i) {
    const int mbase = tile_m + wm + i * 16 + quad * 4;
#pragma unroll
    for (int j = 0; j < 4; ++j) {
      const int n  = tile_n + wn + j * 16 + l16;
      const float bv = bias[n];
      const float v0 = acc[i][j][0] + bv, v1 = acc[i][j][1] + bv;
      const float v2 = acc[i][j][2] + bv, v3 = acc[i][j][3] + bv;
      if (OUTBF16) {
        u16* cp = reinterpret_cast<u16*>(Cout) + (size_t)mbase * N + n;
        const uint32_t p01 = pk2(v0, v1), p23 = pk2(v2, v3);
        if (mbase + 0 < Mstore) cp[0]            = (u16)p01;
        if (mbase + 1 < Mstore) cp[(size_t)N]    = (u16)(p01 >> 16);
        if (mbase + 2 < Mstore) cp[(size_t)N*2]  = (u16)p23;
        if (mbase + 3 < Mstore) cp[(size_t)N*3]  = (u16)(p23 >> 16);
      } else {
        float* cp = reinterpret_cast<float*>(Cout) + (size_t)mbase * N + n;
        if (mbase + 0 < Mstore) cp[0]           = v0;
        if (mbase + 1 < Mstore) cp[(size_t)N]   = v1;
        if (mbase + 2 < Mstore) cp[(size_t)N*2] = v2;
        if (mbase + 3 < Mstore) cp[(size_t)N*3] = v3;
      }
    }
  }
}

// ---------------- kv partials + exp-sums (vectorized) ----------------------
// Thread t owns c = (t&15)*4 + {0..3}; rows nl == t>>4 (mod 16) of each chunk.
__device__ __forceinline__ void kv_part(
    const u16* __restrict__ qkv, float* __restrict__ kvpart,
    float* __restrict__ kvsum, int bh, int split,
    float* __restrict__ e_s, float* __restrict__ v_s) {
  const int b = bh >> 3, h = bh & 7;
  const int n_start = split * 113;
  const int n_end = min(NTOK, n_start + 113);
  const int t = threadIdx.x;
  const int d = t & 63, cq = t >> 6;
  const int c4 = (t & 15) * 4;
  const u16* kbase = qkv + (size_t)(b * NTOK) * QKVN + CDIM + h * CHD;
  const u16* vbase = kbase + CDIM;
  float acc[16];
#pragma unroll
  for (int i = 0; i < 16; ++i) acc[i] = 0.f;
  f32x4 sp4 = {0.f, 0.f, 0.f, 0.f};

  for (int n0 = n_start; n0 < n_end; n0 += 32) {
    const int nc = min(32, n_end - n0);
    __syncthreads();
    for (int i4 = t; i4 < nc * 16; i4 += 256) {
      const int nl = i4 >> 4;            // i4&15 == t&15 (stride 256)
      const uint2 kk = *reinterpret_cast<const uint2*>(
          &kbase[(size_t)(n0 + nl) * QKVN + c4]);
      const uint2 vv = *reinterpret_cast<const uint2*>(
          &vbase[(size_t)(n0 + nl) * QKVN + c4]);
      f32x4 e4, v4;
      e4[0] = __expf(bflo(kk.x)); e4[1] = __expf(bfhi(kk.x));
      e4[2] = __expf(bflo(kk.y)); e4[3] = __expf(bfhi(kk.y));
      v4[0] = bflo(vv.x); v4[1] = bfhi(vv.x);
      v4[2] = bflo(vv.y); v4[3] = bfhi(vv.y);
      *reinterpret_cast<f32x4*>(&e_s[nl * 64 + c4]) = e4;
      *reinterpret_cast<f32x4*>(&v_s[nl * 64 + c4]) = v4;
      sp4 += e4;
    }
    __syncthreads();
    for (int nl = 0; nl < nc; ++nl) {
      const float vv = v_s[nl * 64 + d];
      const f32x4* ep = reinterpret_cast<const f32x4*>(&e_s[nl * 64 + cq * 16]);
      const f32x4 e0 = ep[0], e1 = ep[1], e2 = ep[2], e3 = ep[3];
      acc[0] += e0[0] * vv; acc[1] += e0[1] * vv; acc[2] += e0[2] * vv; acc[3] += e0[3] * vv;
      acc[4] += e1[0] * vv; acc[5] += e1[1] * vv; acc[6] += e1[2] * vv; acc[7] += e1[3] * vv;
      acc[8] += e2[0] * vv; acc[9] += e2[1] * vv; acc[10] += e2[2] * vv; acc[11] += e2[3] * vv;
      acc[12] += e3[0] * vv; acc[13] += e3[1] * vv; acc[14] += e3[2] * vv; acc[15] += e3[3] * vv;
    }
  }
#pragma unroll
  for (int i = 0; i < 16; ++i) {
    const int c = cq * 16 + i;
    kvpart[(((size_t)bh * KVSPLIT + split) * 64 + c) * 64 + d] = acc[i];
  }
  __syncthreads();
  *reinterpret_cast<f32x4*>(&e_s[t * 4]) = sp4;
  __syncthreads();
  if (t < 64) {
    float S = 0.f;
#pragma unroll
    for (int m = 0; m < 16; ++m)
      S += e_s[((t >> 2) + 16 * m) * 4 + (t & 3)];
    kvsum[((size_t)bh * KVSPLIT + split) * 64 + t] = S;
  }
}

// ---------------- reduce partials -> kvT[bh][d][c] bf16 (B-operand layout) -
__global__ __launch_bounds__(256)
void kv_reduce_kernel(const float* __restrict__ kvpart, const float* __restrict__ kvsum,
                      u16* __restrict__ kvT) {
  const int bh = blockIdx.x;
  const int t = threadIdx.x;
  const int d = t & 63, cq = t >> 6;
#pragma unroll
  for (int cc = 0; cc < 16; ++cc) {
    const int c = cq * 16 + cc;
    float s = 0.f, S = 0.f;
#pragma unroll
    for (int sp = 0; sp < KVSPLIT; ++sp) {
      s += kvpart[(((size_t)bh * KVSPLIT + sp) * 64 + c) * 64 + d];
      S += kvsum[((size_t)bh * KVSPLIT + sp) * 64 + c];
    }
    kvT[(size_t)bh * 4096 + d * 64 + c] = f2bf(s / S);
  }
}

// ---------------- depthwise conv + EV fuse ---------------------------------
template <int KS>
__device__ __forceinline__ void conv_head(
    const u16* __restrict__ qkv, const float* __restrict__ wgt,
    const float* __restrict__ bias, int b, int head, int hh, int yt,
    u16* __restrict__ evbuf, u16* __restrict__ ls, float* __restrict__ wls) {
  constexpr int PAD = KS / 2;
  constexpr int RIN = 4 + 2 * PAD;
  const int t = threadIdx.x;
  const int y0 = yt * 4;
  const u16* vimg = qkv + (size_t)(b * NTOK + 1) * QKVN + 2 * CDIM + head * 64;
  // stage weights for this head group, coalesced
  for (int i = t; i < 64 * KS * KS; i += 256)
    wls[i] = wgt[hh * 64 * KS * KS + i];
  const int c8 = (t & 7) * 8;
  for (int pi = t >> 3; pi < RIN * 28; pi += 32) {
    const int ry = pi / 28, rx = pi - ry * 28;
    const int yy = y0 - PAD + ry;
    uint4 val = {0, 0, 0, 0};
    if (yy >= 0 && yy < 28)
      val = *reinterpret_cast<const uint4*>(vimg + (size_t)(yy * 28 + rx) * QKVN + c8);
    *reinterpret_cast<uint4*>(ls + pi * 64 + c8) = val;
  }
  __syncthreads();
  const int d = t & 63, yl = t >> 6;
  float wr[KS * KS];
#pragma unroll
  for (int i = 0; i < KS * KS; ++i) wr[i] = wls[d * KS * KS + i];
  const float bv = bias[hh * 64 + d];
  float acc[28];
#pragma unroll
  for (int x = 0; x < 28; ++x) acc[x] = bv;
#pragma unroll
  for (int xx = 0; xx < 28; ++xx) {
    float col[KS];
#pragma unroll
    for (int r = 0; r < KS; ++r)
      col[r] = bf2f(ls[((yl + r) * 28 + xx) * 64 + d]);
#pragma unroll
    for (int j = 0; j < KS; ++j) {
      const int x = xx + PAD - j;
      if (x >= 0 && x < 28) {
#pragma unroll
        for (int r = 0; r < KS; ++r)
          acc[x] += col[r] * wr[r * KS + j];
      }
    }
  }
  const int p0 = (y0 + yl) * 28;
  const u16* qrow = qkv + (size_t)(b * NTOK + 1 + p0) * QKVN + head * 64 + d;
  u16* obase = evbuf + (((size_t)(b * 8 + head)) * IMGHW + p0) * 64 + d;
#pragma unroll
  for (int x = 0; x < 28; ++x) {
    const float ev = acc[x] * bf2f(qrow[(size_t)x * QKVN]);
    obase[(size_t)x * 64] = f2bf(ev);
  }
}

// ---------------- merged kv + conv (independent work, one launch) ----------
// grid (256, KVSPLIT + 7): y < KVSPLIT -> kv split y; else conv yt = y-KVSPLIT.
__global__ __launch_bounds__(256)
void kv_conv_kernel(const u16* __restrict__ qkv, float* __restrict__ kvpart,
                    float* __restrict__ kvsum,
                    const float* __restrict__ w3, const float* __restrict__ b3,
                    const float* __restrict__ w5, const float* __restrict__ b5,
                    const float* __restrict__ w7, const float* __restrict__ b7,
                    u16* __restrict__ evbuf) {
  __shared__ __align__(16) char smem[10 * 28 * 64 * 2 + 64 * 49 * 4];  // 48.4 KB
  const int y = blockIdx.y;
  if (y < KVSPLIT) {
    float* e_s = reinterpret_cast<float*>(smem);
    float* v_s = e_s + 32 * 64;
    kv_part(qkv, kvpart, kvsum, blockIdx.x, y, e_s, v_s);
  } else {
    u16* ls = reinterpret_cast<u16*>(smem);
    float* wls = reinterpret_cast<float*>(smem + 10 * 28 * 64 * 2);
    const int b = blockIdx.x >> 3, h = blockIdx.x & 7, yt = y - KVSPLIT;
    if (h < 2)      conv_head<3>(qkv, w3, b3, b, h, h,     yt, evbuf, ls, wls);
    else if (h < 5) conv_head<5>(qkv, w5, b5, b, h, h - 2, yt, evbuf, ls, wls);
    else            conv_head<7>(qkv, w7, b7, b, h, h - 5, yt, evbuf, ls, wls);
  }
}

// ---------------- combine: factor_att via MFMA + CRPE ----------------------
// Epilogue: two 128-row halves through f32 LDS (XOR-swizzled 16B chunks),
// then per-thread half-row ownership -> vectorized evbuf reads + attn stores.
__global__ __launch_bounds__(256)
void combine_kernel(const u16* __restrict__ qkv, const u16* __restrict__ kvT,
                    const u16* __restrict__ evbuf, u16* __restrict__ attn) {
  __shared__ __align__(16) float sa[128 * 64];   // 32 KB (one half)
  const int bh = blockIdx.x;
  const int b = bh >> 3, h = bh & 7;
  const int t = threadIdx.x;
  const int wave = t >> 6, lane = t & 63;
  const int quad = lane >> 4, l16 = lane & 15;
  const int tokbase = blockIdx.y * 256 + wave * 64;

  const u16* kvb = kvT + (size_t)bh * 4096;
  bf16x8 bfr[4][2];
#pragma unroll
  for (int j = 0; j < 4; ++j)
#pragma unroll
    for (int kk = 0; kk < 2; ++kk)
      bfr[j][kk] = *reinterpret_cast<const bf16x8*>(
          &kvb[(j * 16 + l16) * 64 + kk * 32 + quad * 8]);

  bf16x8 af[4][2];
#pragma unroll
  for (int i = 0; i < 4; ++i) {
    const int tok = min(tokbase + i * 16 + l16, NTOK - 1);
    const u16* qrow = qkv + (size_t)(b * NTOK + tok) * QKVN + h * CHD;
    af[i][0] = *reinterpret_cast<const bf16x8*>(&qrow[quad * 8]);
    af[i][1] = *reinterpret_cast<const bf16x8*>(&qrow[32 + quad * 8]);
  }

  f32x4 acc[4][4] = {};
#pragma unroll
  for (int kk = 0; kk < 2; ++kk)
#pragma unroll
    for (int i = 0; i < 4; ++i)
#pragma unroll
      for (int j = 0; j < 4; ++j)
        acc[i][j] = __builtin_amdgcn_mfma_f32_16x16x32_bf16(af[i][kk], bfr[j][kk], acc[i][j], 0, 0, 0);

  const float scale = 0.125f;
  const u16* evb = evbuf + (size_t)bh * IMGHW * 64;
#pragma unroll
  for (int half = 0; half < 2; ++half) {
    // phase 1: the two waves owning this half write scale*acc (f32, swizzled)
    if ((wave >> 1) == half) {
      const int rbase = (wave & 1) * 64;
#pragma unroll
      for (int i = 0; i < 4; ++i)
#pragma unroll
        for (int rr = 0; rr < 4; ++rr) {
          const int rl = rbase + i * 16 + quad * 4 + rr;
#pragma unroll
          for (int j = 0; j < 4; ++j) {
            const int dd = j * 16 + l16;
            sa[rl * 64 + (((dd >> 2) ^ (rl & 15)) * 4) + (dd & 3)] =
                scale * acc[i][j][rr];
          }
        }
    }
    __syncthreads();
    // phase 2: thread t owns half-row (rl = t>>1, d-half = t&1)
    {
      const int rl = t >> 1;
      const int tok = blockIdx.y * 256 + half * 128 + rl;
      if (tok < NTOK) {
        u16* orow = attn + (size_t)(b * NTOK + tok) * CDIM + h * CHD;
        const int cb = (t & 1) * 8;
#pragma unroll
        for (int c2 = 0; c2 < 4; ++c2) {
          const int ch0 = cb + c2 * 2;
          const f32x4 v0 = *reinterpret_cast<const f32x4*>(
              &sa[rl * 64 + ((ch0 ^ (rl & 15)) * 4)]);
          const f32x4 v1 = *reinterpret_cast<const f32x4*>(
              &sa[rl * 64 + (((ch0 + 1) ^ (rl & 15)) * 4)]);
          float o0 = v0[0], o1 = v0[1], o2 = v0[2], o3 = v0[3];
          float o4 = v1[0], o5 = v1[1], o6 = v1[2], o7 = v1[3];
          if (tok > 0) {
            const uint4 ev = *reinterpret_cast<const uint4*>(
                &evb[(size_t)(tok - 1) * 64 + ch0 * 4]);
            o0 += bflo(ev.x); o1 += bfhi(ev.x);
            o2 += bflo(ev.y); o3 += bfhi(ev.y);
            o4 += bflo(ev.z); o5 += bfhi(ev.z);
            o6 += bflo(ev.w); o7 += bfhi(ev.w);
          }
          uint4 ow;
          ow.x = pk2(o0, o1); ow.y = pk2(o2, o3);
          ow.z = pk2(o4, o5); ow.w = pk2(o6, o7);
          *reinterpret_cast<uint4*>(&orow[ch0 * 4]) = ow;
        }
      }
    }
    __syncthreads();   // guard sa reuse by next half
  }
}

// ---------------- launch ---------------------------------------------------
extern "C" void kernel_launch(void* const* d_in, const int* in_sizes, int n_in,
                              void* d_out, int out_size, void* d_ws, size_t ws_size,
                              hipStream_t stream) {
  const float* x      = (const float*)d_in[0];
  const float* qkv_w  = (const float*)d_in[1];
  const float* qkv_b  = (const float*)d_in[2];
  const float* proj_w = (const float*)d_in[3];
  const float* proj_b = (const float*)d_in[4];
  const float* w3 = (const float*)d_in[5];
  const float* b3 = (const float*)d_in[6];
  const float* w5 = (const float*)d_in[7];
  const float* b5 = (const float*)d_in[8];
  const float* w7 = (const float*)d_in[9];
  const float* b7 = (const float*)d_in[10];
  float* out = (float*)d_out;

  char* p = (char*)d_ws;
  u16* xb    = (u16*)p;   p += (size_t)MPAD * CDIM * 2;
  u16* wqb   = (u16*)p;   p += (size_t)QKVN * CDIM * 2;
  u16* wpb   = (u16*)p;   p += (size_t)CDIM * CDIM * 2;
  u16* qkvb  = (u16*)p;   p += (size_t)MPAD * QKVN * 2;
  float* kvsum = (float*)p; p += (size_t)256 * KVSPLIT * 64 * 4;
  u16* kvT   = (u16*)p;   p += (size_t)256 * 64 * 64 * 2;
  float* kvpart = (float*)p; p += (size_t)256 * KVSPLIT * 64 * 64 * 4;
  u16* attn  = (u16*)p;   p += (size_t)MPAD * CDIM * 2;
  // evbuf reuses xb (dead after gemm1): 256*784*64*2 = 25.7 MB <= 25.9 MB.
  u16* evbuf = xb;

  // 1. casts (single launch)
  {
    const int total = MROWS * CDIM / 4 + QKVN * CDIM / 4 + CDIM * CDIM / 4;
    casts_kernel<<<(total + 255) / 256, 256, 0, stream>>>(x, xb, qkv_w, wqb, proj_w, wpb);
  }
  // 2. qkv = x @ qkv_w^T + qkv_b  (bf16 out). nMt=99, nNt=12, XCD-banded grid.
  gemm_bt<1><<<13 * 8 * 12, 512, 0, stream>>>(xb, wqb, qkv_b, qkvb,
                                              MPAD, QKVN, CDIM, 99, 12);
  // 3. kv partials + exp-sums, and depthwise convs + EV fuse (merged)
  kv_conv_kernel<<<dim3(256, KVSPLIT + 7), 256, 0, stream>>>(
      qkvb, kvpart, kvsum, w3, b3, w5, b5, w7, b7, evbuf);
  kv_reduce_kernel<<<256, 256, 0, stream>>>(kvpart, kvsum, kvT);
  // 4. factor_att + CRPE -> attn (bf16)
  combine_kernel<<<dim3(256, 4), 256, 0, stream>>>(qkvb, kvT, evbuf, attn);
  // 5. out = attn @ proj_w^T + proj_b  (f32 out). nMt=99, nNt=4.
  gemm_bt<0><<<13 * 8 * 4, 512, 0, stream>>>(attn, wpb, proj_b, out,
                                             MROWS, CDIM, CDIM, 99, 4);
}